// Round 6
// baseline (282.771 us; speedup 1.0000x reference)
//
#include <hip/hip_runtime.h>

// Floyd-Steinberg dithering, BIT_WIDTH=1. 96 images of 512x512 fp32.
// Round 13 (R5 fix): same as R5, with the mid-block `#pragma clang fp`
// moved into a braced compound statement (compile fix).
//  - dither: proven R1 8-wave structure + fmac bit-accumulation
//    (qn in {0,1} -> acc += qn * 2^k, one v_fmac_f32/step, exact < 2^24;
//    window close = 3x v_cvt_u32_f32 + shifts per 64 steps)
//  - fused unpack tail (validated R4): bits -> padded LDS [11][65],
//    each wave writes its 64 rows as coalesced float4s. No unpack kernel.
//  - pack: async-stage split (T14): issue tile t+1 global loads at round
//    top, pp+ds_write after emission(t) -> HBM latency hidden.
// R4 lesson: keep 8 waves (2/SIMD); 1 wave/SIMD exposes chain stalls.
// R3 lesson: ~114 us of dur_us is fixed harness overhead.
// Bit-exactness (R1-R12, absmax 0.0): ref op order, rintf (round-half-
// even), contract OFF on the chain, med3==clamp for non-NaN, -8 sentinel
// makes out-of-range err==0 exactly.

#define F_UL 0.0625f   // 1/16
#define F_U  0.3125f   // 5/16
#define F_UR 0.1875f   // 3/16
#define F_L  0.4375f   // 7/16

typedef unsigned long long ull;

constexpr int WW    = 512;
constexpr int IMG   = WW * WW;
constexpr int NIMG  = 96;
constexpr int NW    = 8;      // waves per dither block / bands per image
constexpr int BUFW  = 792;    // boundary region floats (+128 base offset)
constexpr int NCH   = 40;     // 16-step chunks (640 steps per wave)
constexpr int LAG   = 10;     // producer lead in chunks
constexpr int PPAIR = 320;    // step-pairs per (img,band) region
constexpr size_t XP_FLOATS = (size_t)NIMG * NW * PPAIR * 128;
constexpr size_t XP_BYTES  = XP_FLOATS * 4;        // 125,829,120 B
constexpr size_t XP_SLACK  = 8192;                 // prefetch overrun (16 pairs)
constexpr size_t XP_OFF    = 4u * 1024 * 1024;
constexpr size_t WS_NEED   = XP_OFF + XP_BYTES + XP_SLACK;

__device__ __forceinline__ float wave_shr1(float v, float fill) {
  int r = __builtin_amdgcn_update_dpp(__float_as_int(fill), __float_as_int(v),
                                      0x138 /*wave_shr:1*/, 0xF, 0xF, false);
  return __int_as_float(r);
}

__device__ __forceinline__ float pp(float xv) {   // x -> x01, ref op order
#pragma clang fp contract(off)
  float xc = fminf(fmaxf(xv, -1.0f), 1.0f);
  return (xc + 1.0f) * 0.5f;
}

// ---------------- pack: x -> skewed xp, async-staged loads -----------------
__global__ __launch_bounds__(256)
void pack_kernel(const float* __restrict__ xin, float* __restrict__ xp) {
  __shared__ float ring[4 * 4160];     // 4 slots x 64*65 floats
  const int img = blockIdx.x, w = blockIdx.y;
  const int tid = threadIdx.x;
  const int wv  = tid >> 6, l = tid & 63;

  const float* xg = xin + (size_t)img * IMG + (size_t)w * 64 * WW;
  float* ob = xp + ((size_t)(img * NW + w) * PPAIR) * 128;

  float4 rv[4];                        // staged tile (16 floats/thread)
  auto issue_tile = [&](int t) {       // global -> regs (no wait here)
    const float* src = xg + 64 * t;
#pragma unroll
    for (int k = 0; k < 4; ++k) {
      int flat = tid + 256 * k;
      int row = flat >> 4, cq = flat & 15;
      rv[k] = *(const float4*)(src + row * WW + cq * 4);
    }
  };
  auto write_tile = [&](int t) {       // regs -> LDS slot t&3 (pp applied)
    float* dst = ring + (t & 3) * 4160;
#pragma unroll
    for (int k = 0; k < 4; ++k) {
      int flat = tid + 256 * k;
      int row = flat >> 4, cq = flat & 15;
      float* d = dst + row * 65 + cq * 4;
      d[0] = pp(rv[k].x); d[1] = pp(rv[k].y);
      d[2] = pp(rv[k].z); d[3] = pp(rv[k].w);
    }
  };

  issue_tile(0);
  write_tile(0);                       // compiler inserts the vmcnt wait
  __syncthreads();
  // round t emits pairs 32t..32t+31 (reads tiles t-2..t); tile t+1 loads
  // issued at round top, written to slot (t+1)&3 (disjoint) after emission.
  for (int t = 0; t < 10; ++t) {
    if (t < 7) issue_tile(t + 1);
    const int Mb = 32 * t + 8 * wv;
#pragma unroll
    for (int i = 0; i < 8; ++i) {
      const int M  = Mb + i;
      const int g  = 2 * (M - l);            // global column of first element
      const int gm = g & 511;                // safe LDS index for invalid g
      const int idx = ((gm >> 6) & 3) * 4160 + l * 65 + (gm & 63);
      const bool ok = ((unsigned)g < 512u);
      float va = ring[idx], vb = ring[idx + 1];   // bank (2M-l)%32: 2-way, free
      float2 v = make_float2(ok ? va : -8.0f, ok ? vb : -8.0f);
      *(float2*)(ob + (size_t)M * 128 + 2 * l) = v;   // 512B coalesced / wave
    }
    if (t < 7) write_tile(t + 1);      // vmcnt hidden under emission above
    __syncthreads();
  }
}

// -------- dither: 8 waves, packed x in, fmac bit-accum, fused unpack -------
__global__ __launch_bounds__(512, 1)
void dither_packed(const float* __restrict__ xp, float* __restrict__ yout) {
  __shared__ float bnd[(NW + 1) * BUFW];
  __shared__ int   flags[NW];
  __shared__ ull   bits[NW][11][65];   // [band][window(+pad)][row(+pad)]

  const int  tid  = threadIdx.x;
  const int  wave = tid >> 6;
  const int  lane = tid & 63;
  const int  img  = blockIdx.x;
  const bool l63  = (lane == 63);

  for (int i = tid; i < (NW + 1) * BUFW; i += 512) bnd[i] = 0.0f;
  if (tid < NW) flags[tid] = 0;
  bits[wave][10][lane] = 0ull;         // pad window (t64+1 == 10 reads)
  __syncthreads();

  const float* xw = xp + ((size_t)(img * NW + wave) * PPAIR) * 128 + lane * 2;
  float* bufR = bnd + wave * BUFW;
  float* bufW = bnd + (wave + 1) * BUFW;

  // x pipeline: 8 slots x 4 float2. iter8 K consumes slot K%8, loads slot
  // (K+4)%8 with pairs for iter8 K+4 -> loads live 4 iter8s, zero copies.
  float2 X0[4], X1[4], X2[4], X3[4], X4[4], X5[4], X6[4], X7[4];
#pragma unroll
  for (int i = 0; i < 4; ++i) {
    X0[i] = *(const float2*)(xw + (size_t)(0  + i) * 128);
    X1[i] = *(const float2*)(xw + (size_t)(4  + i) * 128);
    X2[i] = *(const float2*)(xw + (size_t)(8  + i) * 128);
    X3[i] = *(const float2*)(xw + (size_t)(12 + i) * 128);
  }

  int seen = 0;                        // cached producer flag (monotonic)
  if (wave) {
    while ((seen = __hip_atomic_load(&flags[wave - 1], __ATOMIC_RELAXED,
                                     __HIP_MEMORY_SCOPE_WORKGROUP)) < LAG)
      __builtin_amdgcn_s_sleep(1);
    __asm__ volatile("s_waitcnt lgkmcnt(0)" ::: "memory");
  }

  float err = 0.0f, s2 = 0.0f;
  float s1 = (lane == 0) ? bufR[129] : 0.0f;
  // q pipeline: 2 slots, parity K%2; reloaded at iter8 bottom for K+2.
  float2 Q0[4], Q1[4];
#pragma unroll
  for (int i = 0; i < 4; ++i) {
    Q0[i] = *(const float2*)(bufR + 130 + 2 * i);   // for K=0 (steps 0..7)
    Q1[i] = *(const float2*)(bufR + 138 + 2 * i);   // for K=1 (steps 8..15)
  }

  // float bit accumulators: A = window bits 0..23, B = 24..47, C = 48..63.
  float accA = 0.0f, accB = 0.0f, accC = 0.0f;

  auto step = [&](float qv, float xv) -> float {
#pragma clang fp contract(off)
    float e_in = wave_shr1(err, qv);          // err[r-1][c+1]
    float t1   = F_UL * s2;
    float t2   = F_U  * s1;
    float t3   = F_UR * e_in;
    float u    = (t1 + t2) + t3;              // ref's left-to-right order
    float a1   = xv + u;                      // xv = x01 (or -8 sentinel)
    float b    = F_L * err;
    float v    = a1 + b;
    float val  = __builtin_amdgcn_fmed3f(v, 0.0f, 1.0f);  // == clamp
    float qn   = rintf(val);                  // round-half-even
    err = val - qn;                           // sentinel path: exactly 0
    s2 = s1; s1 = e_in;
    return qn;                                // 0.0f or 1.0f
  };

  auto iter8 = [&](float2 (&XC)[4], float2 (&XL)[4], float2 (&QC)[4],
                   int T, float& acc, float W) {
    // x prefetch: pairs T/2+16..19 (consumed 4 iter8s later, slot renamed)
    const float* lp = xw + (size_t)(T / 2 + 16) * 128;
    XL[0] = *(const float2*)(lp + 0 * 128);
    XL[1] = *(const float2*)(lp + 1 * 128);
    XL[2] = *(const float2*)(lp + 2 * 128);
    XL[3] = *(const float2*)(lp + 3 * 128);

    float p0 = step(QC[0].x, XC[0].x); float e0 = err;
    float p1 = step(QC[0].y, XC[0].y); float e1 = err;
    float p2 = step(QC[1].x, XC[1].x); float e2 = err;
    float p3 = step(QC[1].y, XC[1].y); float e3 = err;
    float p4 = step(QC[2].x, XC[2].x); float e4 = err;
    float p5 = step(QC[2].y, XC[2].y); float e5 = err;
    float p6 = step(QC[3].x, XC[3].x); float e6 = err;
    float p7 = step(QC[3].y, XC[3].y); float e7 = err;

    // boundary prefetch for iteration T+16 (same slot, distance 2)
    QC[0] = *(const float2*)(bufR + (T + 146));
    QC[1] = *(const float2*)(bufR + (T + 148));
    QC[2] = *(const float2*)(bufR + (T + 150));
    QC[3] = *(const float2*)(bufR + (T + 152));

    // bit accumulate: qn in {0,1}; one v_fmac_f32 per step, exact (< 2^24)
    {
#pragma clang fp contract(off)
      acc += p0 * (W * 1.0f);
      acc += p1 * (W * 2.0f);
      acc += p2 * (W * 4.0f);
      acc += p3 * (W * 8.0f);
      acc += p4 * (W * 16.0f);
      acc += p5 * (W * 32.0f);
      acc += p6 * (W * 64.0f);
      acc += p7 * (W * 128.0f);
    }

    if (l63) {  // boundary row for next wave; base = T-126+129 = T+3
      float* bw = bufW + (T + 3);
      bw[0] = e0; bw[1] = e1; bw[2] = e2; bw[3] = e3;
      bw[4] = e4; bw[5] = e5; bw[6] = e6; bw[7] = e7;
    }
  };

  auto waitflag = [&](int j) {
    if (wave) {
      int need = j + LAG; if (need > NCH) need = NCH;
      if (seen < need) {
        while ((seen = __hip_atomic_load(&flags[wave - 1], __ATOMIC_RELAXED,
                                         __HIP_MEMORY_SCOPE_WORKGROUP)) < need)
          __builtin_amdgcn_s_sleep(1);
        __asm__ volatile("s_waitcnt lgkmcnt(0)" ::: "memory");
      }
    }
  };
  auto pubflag = [&](int v) {
    if (l63) {
      __asm__ volatile("s_waitcnt lgkmcnt(0)" ::: "memory");
      __hip_atomic_store(&flags[wave], v, __ATOMIC_RELAXED,
                         __HIP_MEMORY_SCOPE_WORKGROUP);
    }
  };

  // body = 4 chunks = 8 iter8s = one 64-step bit window
  for (int jj = 0; jj < NCH; jj += 4) {
    const int T0 = 16 * jj;
    waitflag(jj);
    iter8(X0, X4, Q0, T0 + 0,  accA, 1.0f);
    iter8(X1, X5, Q1, T0 + 8,  accA, 256.0f);
    pubflag(jj + 1);
    waitflag(jj + 1);
    iter8(X2, X6, Q0, T0 + 16, accA, 65536.0f);
    iter8(X3, X7, Q1, T0 + 24, accB, 1.0f);
    pubflag(jj + 2);
    waitflag(jj + 2);
    iter8(X4, X0, Q0, T0 + 32, accB, 256.0f);
    iter8(X5, X1, Q1, T0 + 40, accB, 65536.0f);
    pubflag(jj + 3);
    waitflag(jj + 3);
    iter8(X6, X2, Q0, T0 + 48, accC, 1.0f);
    iter8(X7, X3, Q1, T0 + 56, accC, 256.0f);
    pubflag(jj + 4);
    // window close: exact integer reconstruction
    unsigned u0 = (unsigned)accA;          // bits 0..23
    unsigned u1 = (unsigned)accB;          // bits 24..47
    unsigned u2 = (unsigned)accC;          // bits 48..63
    unsigned lo = u0 | (u1 << 24);
    unsigned hi = (u1 >> 8) | (u2 << 16);
    *(uint2*)&bits[wave][jj >> 2][lane] = make_uint2(lo, hi);
    accA = 0.0f; accB = 0.0f; accC = 0.0f;
  }

  // ---- unpack tail: this wave's 64 rows, bits (LDS) -> ±1.0f coalesced ----
  float* ybase = yout + (size_t)img * IMG + (size_t)(wave * 64) * WW + 8 * lane;
  for (int rr = 0; rr < 64; ++rr) {
    const int t0 = 8 * lane + 2 * rr;         // first bit index
    const int t64 = t0 >> 6, sh = t0 & 63;    // sh even, <= 62
    ull w1 = bits[wave][t64][rr];
    ull w2 = bits[wave][t64 + 1][rr];         // pad window covers t64==9
    unsigned b = (unsigned)((w1 >> sh) | ((w2 << 1) << (63 - sh)));
    float* orow = ybase + (size_t)rr * WW;
    float4 v0, v1;
    v0.x = (b & 1u)   ? 1.0f : -1.0f;
    v0.y = (b & 2u)   ? 1.0f : -1.0f;
    v0.z = (b & 4u)   ? 1.0f : -1.0f;
    v0.w = (b & 8u)   ? 1.0f : -1.0f;
    v1.x = (b & 16u)  ? 1.0f : -1.0f;
    v1.y = (b & 32u)  ? 1.0f : -1.0f;
    v1.z = (b & 64u)  ? 1.0f : -1.0f;
    v1.w = (b & 128u) ? 1.0f : -1.0f;
    *(float4*)(orow)     = v0;
    *(float4*)(orow + 4) = v1;
  }
}

// ---------------- fallback: R4/R6 direct-x kernel (known-good) --------------
__global__ __launch_bounds__(512, 1)
void dither_direct(const float* __restrict__ xin, float* __restrict__ yout) {
  __shared__ float bnd[(NW + 1) * BUFW];
  __shared__ int flags[NW];

  const int  tid  = threadIdx.x;
  const int  wave = tid >> 6;
  const int  lane = tid & 63;
  const int  img  = blockIdx.x;
  const bool l63  = (lane == 63);

  for (int i = tid; i < (NW + 1) * BUFW; i += 512) bnd[i] = 0.0f;
  if (tid < NW) flags[tid] = 0;
  __syncthreads();

  const int r = wave * 64 + lane;
  const float* xrow = xin + (size_t)img * IMG + (size_t)r * WW;
  float*       yrow = yout + (size_t)img * IMG + (size_t)r * WW;
  float* bufR = bnd + wave * BUFW;
  float* bufW = bnd + (wave + 1) * BUFW;
  const int c0 = -2 * lane;

  auto ldx = [&](int c) -> float2 { return *(const float2*)(xrow + (c & 511)); };

  float2 A0 = ldx(c0 + 0),  A1 = ldx(c0 + 2),  A2 = ldx(c0 + 4),  A3 = ldx(c0 + 6);
  float2 pB0 = ldx(c0 + 8),  pB1 = ldx(c0 + 10), pB2 = ldx(c0 + 12), pB3 = ldx(c0 + 14);
  float2 pC0 = ldx(c0 + 16), pC1 = ldx(c0 + 18), pC2 = ldx(c0 + 20), pC3 = ldx(c0 + 22);
  float xq0 = pp(A0.x), xq1 = pp(A0.y), xq2 = pp(A1.x), xq3 = pp(A1.y);
  float xq4 = pp(A2.x), xq5 = pp(A2.y), xq6 = pp(A3.x), xq7 = pp(A3.y);
  float2 pA0 = pB0, pA1 = pB1, pA2 = pB2, pA3 = pB3;
  pB0 = pC0; pB1 = pC1; pB2 = pC2; pB3 = pC3;

  if (wave) {
    while (__hip_atomic_load(&flags[wave - 1], __ATOMIC_RELAXED,
                             __HIP_MEMORY_SCOPE_WORKGROUP) < LAG)
      __builtin_amdgcn_s_sleep(1);
    __asm__ volatile("s_waitcnt lgkmcnt(0)" ::: "memory");
  }

  float err = 0.0f, s2 = 0.0f;
  float s1 = (lane == 0) ? bufR[129] : 0.0f;
  float2 qa = *(const float2*)(bufR + 130);
  float2 qb = *(const float2*)(bufR + 132);
  float2 qc = *(const float2*)(bufR + 134);
  float2 qd = *(const float2*)(bufR + 136);
  float2 fa = *(const float2*)(bufR + 138);
  float2 fb = *(const float2*)(bufR + 140);
  float2 fc = *(const float2*)(bufR + 142);
  float2 fd = *(const float2*)(bufR + 144);

  auto step = [&](int c, float qv, float xv) -> float {
#pragma clang fp contract(off)
    float e_in = wave_shr1(err, qv);
    float t1   = F_UL * s2;
    float t2   = F_U  * s1;
    float t3   = F_UR * e_in;
    float u    = (t1 + t2) + t3;
    float a1   = xv + u;
    float b    = F_L * err;
    float v    = a1 + b;
    float val  = fminf(fmaxf(v, 0.0f), 1.0f);
    float qn   = rintf(val);
    float e    = val - qn;
    float en   = ((unsigned)c < 512u) ? e : 0.0f;
    err = en; s2 = s1; s1 = e_in;
    return __builtin_fmaf(qn, 2.0f, -1.0f);
  };

  auto iter8 = [&](int T) {
    const int cg = c0 + T;
    float2 n0 = ldx(cg + 24), n1 = ldx(cg + 26), n2 = ldx(cg + 28), n3 = ldx(cg + 30);
    float2 h0 = *(const float2*)(bufR + (T + 146));
    float2 h1 = *(const float2*)(bufR + (T + 148));
    float2 h2 = *(const float2*)(bufR + (T + 150));
    float2 h3 = *(const float2*)(bufR + (T + 152));
    float w0 = pp(pA0.x), w1 = pp(pA0.y), w2 = pp(pA1.x), w3 = pp(pA1.y);
    float w4 = pp(pA2.x), w5 = pp(pA2.y), w6 = pp(pA3.x), w7 = pp(pA3.y);

    float y0 = step(cg + 0, qa.x, xq0); float e0 = err;
    float y1 = step(cg + 1, qa.y, xq1); float e1 = err;
    float y2 = step(cg + 2, qb.x, xq2); float e2 = err;
    float y3 = step(cg + 3, qb.y, xq3); float e3 = err;
    float y4 = step(cg + 4, qc.x, xq4); float e4 = err;
    float y5 = step(cg + 5, qc.y, xq5); float e5 = err;
    float y6 = step(cg + 6, qd.x, xq6); float e6 = err;
    float y7 = step(cg + 7, qd.y, xq7); float e7 = err;

    if ((unsigned)(cg + 0) < 511u) *(float2*)(yrow + cg + 0) = make_float2(y0, y1);
    if ((unsigned)(cg + 2) < 511u) *(float2*)(yrow + cg + 2) = make_float2(y2, y3);
    if ((unsigned)(cg + 4) < 511u) *(float2*)(yrow + cg + 4) = make_float2(y4, y5);
    if ((unsigned)(cg + 6) < 511u) *(float2*)(yrow + cg + 6) = make_float2(y6, y7);

    if (l63) {
      float* bw = bufW + (cg + 129);
      bw[0] = e0; bw[1] = e1; bw[2] = e2; bw[3] = e3;
      bw[4] = e4; bw[5] = e5; bw[6] = e6; bw[7] = e7;
    }

    xq0 = w0; xq1 = w1; xq2 = w2; xq3 = w3;
    xq4 = w4; xq5 = w5; xq6 = w6; xq7 = w7;
    pA0 = pB0; pA1 = pB1; pA2 = pB2; pA3 = pB3;
    pB0 = n0;  pB1 = n1;  pB2 = n2;  pB3 = n3;
    qa = fa; qb = fb; qc = fc; qd = fd;
    fa = h0; fb = h1; fc = h2; fd = h3;
  };

  for (int j = 0; j < NCH; ++j) {
    if (wave) {
      int need = j + LAG; if (need > NCH) need = NCH;
      while (__hip_atomic_load(&flags[wave - 1], __ATOMIC_RELAXED,
                               __HIP_MEMORY_SCOPE_WORKGROUP) < need)
        __builtin_amdgcn_s_sleep(1);
      __asm__ volatile("s_waitcnt lgkmcnt(0)" ::: "memory");
    }
    iter8(16 * j);
    iter8(16 * j + 8);
    if (l63) {
      __asm__ volatile("s_waitcnt lgkmcnt(0)" ::: "memory");
      __hip_atomic_store(&flags[wave], j + 1, __ATOMIC_RELAXED,
                         __HIP_MEMORY_SCOPE_WORKGROUP);
    }
  }
}

extern "C" void kernel_launch(void* const* d_in, const int* in_sizes, int n_in,
                              void* d_out, int out_size, void* d_ws, size_t ws_size,
                              hipStream_t stream) {
  const float* x = (const float*)d_in[0];
  float*       y = (float*)d_out;
  if (ws_size >= WS_NEED) {
    float* xp = (float*)((char*)d_ws + XP_OFF);
    pack_kernel<<<dim3(NIMG, NW), dim3(256), 0, stream>>>(x, xp);
    dither_packed<<<dim3(NIMG), dim3(512), 0, stream>>>(xp, y);
  } else {
    dither_direct<<<dim3(NIMG), dim3(512), 0, stream>>>(x, y);
  }
}

// Round 8
// 279.389 us; speedup vs baseline: 1.0121x; 1.0121x over previous
//
#include <hip/hip_runtime.h>

// Floyd-Steinberg dithering, BIT_WIDTH=1. 96 images of 512x512 fp32.
// Round 15 (R7 resubmit; R7 bench was an infra failure, not a kernel fail).
// Conservation analysis (R1/R4/R6 all 282.7) shows the dither kernel is
// issue-throughput-bound: work moves 1:1 into time. So: delete instructions,
// don't move them.
//  - dither tail: 16-entry float4 LDS LUT for bits->±1.0f (nibble-indexed,
//    ~10 instrs/row vs 27; entries stride 16B -> <=2-way bank alias + lane
//    broadcast). Everything else byte-identical to R6's validated kernel.
//  - pack: 512 threads/block (8 waves, 2 blocks/CU = 16 waves/CU) -- pack is
//    latency-exposed at its round barriers (70 us for 226 MB = 3.2 TB/s);
//    more waves halve per-wave work per round. Emission indexing (4 pairs/
//    wave) already validated in R2's fused variant. Async-stage retained.
// R6 lesson: fmac bit-accum neutral; fused-tail cost == unpack kernel cost
// (conservation). ~114 us of dur_us is fixed harness overhead.
// Bit-exactness (R1-R13, absmax 0.0): ref op order, rintf (round-half-even),
// contract OFF on the chain, med3==clamp for non-NaN, -8 sentinel makes
// out-of-range err==0 exactly.

#define F_UL 0.0625f   // 1/16
#define F_U  0.3125f   // 5/16
#define F_UR 0.1875f   // 3/16
#define F_L  0.4375f   // 7/16

typedef unsigned long long ull;

constexpr int WW    = 512;
constexpr int IMG   = WW * WW;
constexpr int NIMG  = 96;
constexpr int NW    = 8;      // waves per dither block / bands per image
constexpr int BUFW  = 792;    // boundary region floats (+128 base offset)
constexpr int NCH   = 40;     // 16-step chunks (640 steps per wave)
constexpr int LAG   = 10;     // producer lead in chunks
constexpr int PPAIR = 320;    // step-pairs per (img,band) region
constexpr size_t XP_FLOATS = (size_t)NIMG * NW * PPAIR * 128;
constexpr size_t XP_BYTES  = XP_FLOATS * 4;        // 125,829,120 B
constexpr size_t XP_SLACK  = 8192;                 // prefetch overrun (16 pairs)
constexpr size_t XP_OFF    = 4u * 1024 * 1024;
constexpr size_t WS_NEED   = XP_OFF + XP_BYTES + XP_SLACK;

__device__ __forceinline__ float wave_shr1(float v, float fill) {
  int r = __builtin_amdgcn_update_dpp(__float_as_int(fill), __float_as_int(v),
                                      0x138 /*wave_shr:1*/, 0xF, 0xF, false);
  return __int_as_float(r);
}

__device__ __forceinline__ float pp(float xv) {   // x -> x01, ref op order
#pragma clang fp contract(off)
  float xc = fminf(fmaxf(xv, -1.0f), 1.0f);
  return (xc + 1.0f) * 0.5f;
}

// ---------------- pack: x -> skewed xp, 8 waves, async-staged --------------
__global__ __launch_bounds__(512)
void pack_kernel(const float* __restrict__ xin, float* __restrict__ xp) {
  __shared__ float ring[4 * 4160];     // 4 slots x 64*65 floats
  const int img = blockIdx.x, w = blockIdx.y;
  const int tid = threadIdx.x;
  const int wv  = tid >> 6, l = tid & 63;

  const float* xg = xin + (size_t)img * IMG + (size_t)w * 64 * WW;
  float* ob = xp + ((size_t)(img * NW + w) * PPAIR) * 128;

  float4 rv[2];                        // staged tile (8 floats/thread)
  auto issue_tile = [&](int t) {       // global -> regs (no wait here)
    const float* src = xg + 64 * t;
#pragma unroll
    for (int k = 0; k < 2; ++k) {
      int flat = tid + 512 * k;
      int row = flat >> 4, cq = flat & 15;
      rv[k] = *(const float4*)(src + row * WW + cq * 4);
    }
  };
  auto write_tile = [&](int t) {       // regs -> LDS slot t&3 (pp applied)
    float* dst = ring + (t & 3) * 4160;
#pragma unroll
    for (int k = 0; k < 2; ++k) {
      int flat = tid + 512 * k;
      int row = flat >> 4, cq = flat & 15;
      float* d = dst + row * 65 + cq * 4;
      d[0] = pp(rv[k].x); d[1] = pp(rv[k].y);
      d[2] = pp(rv[k].z); d[3] = pp(rv[k].w);
    }
  };

  issue_tile(0);
  write_tile(0);                       // compiler inserts the vmcnt wait
  __syncthreads();
  // round t emits pairs 32t..32t+31 (reads tiles t-2..t); tile t+1 loads
  // issued at round top, written to slot (t+1)&3 (disjoint) after emission.
  for (int t = 0; t < 10; ++t) {
    if (t < 7) issue_tile(t + 1);
    const int Mb = 32 * t + 4 * wv;    // 8 waves x 4 pairs = 32 pairs/round
#pragma unroll
    for (int i = 0; i < 4; ++i) {
      const int M  = Mb + i;
      const int g  = 2 * (M - l);            // global column of first element
      const int gm = g & 511;                // safe LDS index for invalid g
      const int idx = ((gm >> 6) & 3) * 4160 + l * 65 + (gm & 63);
      const bool ok = ((unsigned)g < 512u);
      float va = ring[idx], vb = ring[idx + 1];   // bank (2M-l)%32: 2-way, free
      float2 v = make_float2(ok ? va : -8.0f, ok ? vb : -8.0f);
      *(float2*)(ob + (size_t)M * 128 + 2 * l) = v;   // 512B coalesced / wave
    }
    if (t < 7) write_tile(t + 1);      // vmcnt hidden under emission above
    __syncthreads();
  }
}

// -------- dither: 8 waves, packed x in, fmac bit-accum, LUT unpack ---------
__global__ __launch_bounds__(512, 1)
void dither_packed(const float* __restrict__ xp, float* __restrict__ yout) {
  __shared__ float bnd[(NW + 1) * BUFW];
  __shared__ int   flags[NW];
  __shared__ ull   bits[NW][11][65];   // [band][window(+pad)][row(+pad)]
  __shared__ float4 lut4[16];          // nibble -> 4x ±1.0f

  const int  tid  = threadIdx.x;
  const int  wave = tid >> 6;
  const int  lane = tid & 63;
  const int  img  = blockIdx.x;
  const bool l63  = (lane == 63);

  for (int i = tid; i < (NW + 1) * BUFW; i += 512) bnd[i] = 0.0f;
  if (tid < NW) flags[tid] = 0;
  if (tid < 16)
    lut4[tid] = make_float4((tid & 1) ? 1.0f : -1.0f, (tid & 2) ? 1.0f : -1.0f,
                            (tid & 4) ? 1.0f : -1.0f, (tid & 8) ? 1.0f : -1.0f);
  bits[wave][10][lane] = 0ull;         // pad window (t64+1 == 10 reads)
  __syncthreads();

  const float* xw = xp + ((size_t)(img * NW + wave) * PPAIR) * 128 + lane * 2;
  float* bufR = bnd + wave * BUFW;
  float* bufW = bnd + (wave + 1) * BUFW;

  // x pipeline: 8 slots x 4 float2. iter8 K consumes slot K%8, loads slot
  // (K+4)%8 with pairs for iter8 K+4 -> loads live 4 iter8s, zero copies.
  float2 X0[4], X1[4], X2[4], X3[4], X4[4], X5[4], X6[4], X7[4];
#pragma unroll
  for (int i = 0; i < 4; ++i) {
    X0[i] = *(const float2*)(xw + (size_t)(0  + i) * 128);
    X1[i] = *(const float2*)(xw + (size_t)(4  + i) * 128);
    X2[i] = *(const float2*)(xw + (size_t)(8  + i) * 128);
    X3[i] = *(const float2*)(xw + (size_t)(12 + i) * 128);
  }

  int seen = 0;                        // cached producer flag (monotonic)
  if (wave) {
    while ((seen = __hip_atomic_load(&flags[wave - 1], __ATOMIC_RELAXED,
                                     __HIP_MEMORY_SCOPE_WORKGROUP)) < LAG)
      __builtin_amdgcn_s_sleep(1);
    __asm__ volatile("s_waitcnt lgkmcnt(0)" ::: "memory");
  }

  float err = 0.0f, s2 = 0.0f;
  float s1 = (lane == 0) ? bufR[129] : 0.0f;
  // q pipeline: 2 slots, parity K%2; reloaded at iter8 bottom for K+2.
  float2 Q0[4], Q1[4];
#pragma unroll
  for (int i = 0; i < 4; ++i) {
    Q0[i] = *(const float2*)(bufR + 130 + 2 * i);   // for K=0 (steps 0..7)
    Q1[i] = *(const float2*)(bufR + 138 + 2 * i);   // for K=1 (steps 8..15)
  }

  // float bit accumulators: A = window bits 0..23, B = 24..47, C = 48..63.
  float accA = 0.0f, accB = 0.0f, accC = 0.0f;

  auto step = [&](float qv, float xv) -> float {
#pragma clang fp contract(off)
    float e_in = wave_shr1(err, qv);          // err[r-1][c+1]
    float t1   = F_UL * s2;
    float t2   = F_U  * s1;
    float t3   = F_UR * e_in;
    float u    = (t1 + t2) + t3;              // ref's left-to-right order
    float a1   = xv + u;                      // xv = x01 (or -8 sentinel)
    float b    = F_L * err;
    float v    = a1 + b;
    float val  = __builtin_amdgcn_fmed3f(v, 0.0f, 1.0f);  // == clamp
    float qn   = rintf(val);                  // round-half-even
    err = val - qn;                           // sentinel path: exactly 0
    s2 = s1; s1 = e_in;
    return qn;                                // 0.0f or 1.0f
  };

  auto iter8 = [&](float2 (&XC)[4], float2 (&XL)[4], float2 (&QC)[4],
                   int T, float& acc, float W) {
    // x prefetch: pairs T/2+16..19 (consumed 4 iter8s later, slot renamed)
    const float* lp = xw + (size_t)(T / 2 + 16) * 128;
    XL[0] = *(const float2*)(lp + 0 * 128);
    XL[1] = *(const float2*)(lp + 1 * 128);
    XL[2] = *(const float2*)(lp + 2 * 128);
    XL[3] = *(const float2*)(lp + 3 * 128);

    float p0 = step(QC[0].x, XC[0].x); float e0 = err;
    float p1 = step(QC[0].y, XC[0].y); float e1 = err;
    float p2 = step(QC[1].x, XC[1].x); float e2 = err;
    float p3 = step(QC[1].y, XC[1].y); float e3 = err;
    float p4 = step(QC[2].x, XC[2].x); float e4 = err;
    float p5 = step(QC[2].y, XC[2].y); float e5 = err;
    float p6 = step(QC[3].x, XC[3].x); float e6 = err;
    float p7 = step(QC[3].y, XC[3].y); float e7 = err;

    // boundary prefetch for iteration T+16 (same slot, distance 2)
    QC[0] = *(const float2*)(bufR + (T + 146));
    QC[1] = *(const float2*)(bufR + (T + 148));
    QC[2] = *(const float2*)(bufR + (T + 150));
    QC[3] = *(const float2*)(bufR + (T + 152));

    // bit accumulate: qn in {0,1}; one v_fmac_f32 per step, exact (< 2^24)
    {
#pragma clang fp contract(off)
      acc += p0 * (W * 1.0f);
      acc += p1 * (W * 2.0f);
      acc += p2 * (W * 4.0f);
      acc += p3 * (W * 8.0f);
      acc += p4 * (W * 16.0f);
      acc += p5 * (W * 32.0f);
      acc += p6 * (W * 64.0f);
      acc += p7 * (W * 128.0f);
    }

    if (l63) {  // boundary row for next wave; base = T-126+129 = T+3
      float* bw = bufW + (T + 3);
      bw[0] = e0; bw[1] = e1; bw[2] = e2; bw[3] = e3;
      bw[4] = e4; bw[5] = e5; bw[6] = e6; bw[7] = e7;
    }
  };

  auto waitflag = [&](int j) {
    if (wave) {
      int need = j + LAG; if (need > NCH) need = NCH;
      if (seen < need) {
        while ((seen = __hip_atomic_load(&flags[wave - 1], __ATOMIC_RELAXED,
                                         __HIP_MEMORY_SCOPE_WORKGROUP)) < need)
          __builtin_amdgcn_s_sleep(1);
        __asm__ volatile("s_waitcnt lgkmcnt(0)" ::: "memory");
      }
    }
  };
  auto pubflag = [&](int v) {
    if (l63) {
      __asm__ volatile("s_waitcnt lgkmcnt(0)" ::: "memory");
      __hip_atomic_store(&flags[wave], v, __ATOMIC_RELAXED,
                         __HIP_MEMORY_SCOPE_WORKGROUP);
    }
  };

  // body = 4 chunks = 8 iter8s = one 64-step bit window
  for (int jj = 0; jj < NCH; jj += 4) {
    const int T0 = 16 * jj;
    waitflag(jj);
    iter8(X0, X4, Q0, T0 + 0,  accA, 1.0f);
    iter8(X1, X5, Q1, T0 + 8,  accA, 256.0f);
    pubflag(jj + 1);
    waitflag(jj + 1);
    iter8(X2, X6, Q0, T0 + 16, accA, 65536.0f);
    iter8(X3, X7, Q1, T0 + 24, accB, 1.0f);
    pubflag(jj + 2);
    waitflag(jj + 2);
    iter8(X4, X0, Q0, T0 + 32, accB, 256.0f);
    iter8(X5, X1, Q1, T0 + 40, accB, 65536.0f);
    pubflag(jj + 3);
    waitflag(jj + 3);
    iter8(X6, X2, Q0, T0 + 48, accC, 1.0f);
    iter8(X7, X3, Q1, T0 + 56, accC, 256.0f);
    pubflag(jj + 4);
    // window close: exact integer reconstruction
    unsigned u0 = (unsigned)accA;          // bits 0..23
    unsigned u1 = (unsigned)accB;          // bits 24..47
    unsigned u2 = (unsigned)accC;          // bits 48..63
    unsigned lo = u0 | (u1 << 24);
    unsigned hi = (u1 >> 8) | (u2 << 16);
    *(uint2*)&bits[wave][jj >> 2][lane] = make_uint2(lo, hi);
    accA = 0.0f; accB = 0.0f; accC = 0.0f;
  }

  // ---- unpack tail: LUT expansion, this wave's 64 rows, coalesced ----
  float* ybase = yout + (size_t)img * IMG + (size_t)(wave * 64) * WW + 8 * lane;
  for (int rr = 0; rr < 64; ++rr) {
    const int t0 = 8 * lane + 2 * rr;         // first bit index
    const int t64 = t0 >> 6, sh = t0 & 63;    // sh even, <= 62
    ull w1 = bits[wave][t64][rr];
    ull w2 = bits[wave][t64 + 1][rr];         // pad window covers t64==9
    unsigned b = (unsigned)((w1 >> sh) | ((w2 << 1) << (63 - sh)));
    float* orow = ybase + (size_t)rr * WW;
    *(float4*)(orow)     = lut4[b & 15u];
    *(float4*)(orow + 4) = lut4[(b >> 4) & 15u];
  }
}

// ---------------- fallback: R4/R6 direct-x kernel (known-good) --------------
__global__ __launch_bounds__(512, 1)
void dither_direct(const float* __restrict__ xin, float* __restrict__ yout) {
  __shared__ float bnd[(NW + 1) * BUFW];
  __shared__ int flags[NW];

  const int  tid  = threadIdx.x;
  const int  wave = tid >> 6;
  const int  lane = tid & 63;
  const int  img  = blockIdx.x;
  const bool l63  = (lane == 63);

  for (int i = tid; i < (NW + 1) * BUFW; i += 512) bnd[i] = 0.0f;
  if (tid < NW) flags[tid] = 0;
  __syncthreads();

  const int r = wave * 64 + lane;
  const float* xrow = xin + (size_t)img * IMG + (size_t)r * WW;
  float*       yrow = yout + (size_t)img * IMG + (size_t)r * WW;
  float* bufR = bnd + wave * BUFW;
  float* bufW = bnd + (wave + 1) * BUFW;
  const int c0 = -2 * lane;

  auto ldx = [&](int c) -> float2 { return *(const float2*)(xrow + (c & 511)); };

  float2 A0 = ldx(c0 + 0),  A1 = ldx(c0 + 2),  A2 = ldx(c0 + 4),  A3 = ldx(c0 + 6);
  float2 pB0 = ldx(c0 + 8),  pB1 = ldx(c0 + 10), pB2 = ldx(c0 + 12), pB3 = ldx(c0 + 14);
  float2 pC0 = ldx(c0 + 16), pC1 = ldx(c0 + 18), pC2 = ldx(c0 + 20), pC3 = ldx(c0 + 22);
  float xq0 = pp(A0.x), xq1 = pp(A0.y), xq2 = pp(A1.x), xq3 = pp(A1.y);
  float xq4 = pp(A2.x), xq5 = pp(A2.y), xq6 = pp(A3.x), xq7 = pp(A3.y);
  float2 pA0 = pB0, pA1 = pB1, pA2 = pB2, pA3 = pB3;
  pB0 = pC0; pB1 = pC1; pB2 = pC2; pB3 = pC3;

  if (wave) {
    while (__hip_atomic_load(&flags[wave - 1], __ATOMIC_RELAXED,
                             __HIP_MEMORY_SCOPE_WORKGROUP) < LAG)
      __builtin_amdgcn_s_sleep(1);
    __asm__ volatile("s_waitcnt lgkmcnt(0)" ::: "memory");
  }

  float err = 0.0f, s2 = 0.0f;
  float s1 = (lane == 0) ? bufR[129] : 0.0f;
  float2 qa = *(const float2*)(bufR + 130);
  float2 qb = *(const float2*)(bufR + 132);
  float2 qc = *(const float2*)(bufR + 134);
  float2 qd = *(const float2*)(bufR + 136);
  float2 fa = *(const float2*)(bufR + 138);
  float2 fb = *(const float2*)(bufR + 140);
  float2 fc = *(const float2*)(bufR + 142);
  float2 fd = *(const float2*)(bufR + 144);

  auto step = [&](int c, float qv, float xv) -> float {
#pragma clang fp contract(off)
    float e_in = wave_shr1(err, qv);
    float t1   = F_UL * s2;
    float t2   = F_U  * s1;
    float t3   = F_UR * e_in;
    float u    = (t1 + t2) + t3;
    float a1   = xv + u;
    float b    = F_L * err;
    float v    = a1 + b;
    float val  = fminf(fmaxf(v, 0.0f), 1.0f);
    float qn   = rintf(val);
    float e    = val - qn;
    float en   = ((unsigned)c < 512u) ? e : 0.0f;
    err = en; s2 = s1; s1 = e_in;
    return __builtin_fmaf(qn, 2.0f, -1.0f);
  };

  auto iter8 = [&](int T) {
    const int cg = c0 + T;
    float2 n0 = ldx(cg + 24), n1 = ldx(cg + 26), n2 = ldx(cg + 28), n3 = ldx(cg + 30);
    float2 h0 = *(const float2*)(bufR + (T + 146));
    float2 h1 = *(const float2*)(bufR + (T + 148));
    float2 h2 = *(const float2*)(bufR + (T + 150));
    float2 h3 = *(const float2*)(bufR + (T + 152));
    float w0 = pp(pA0.x), w1 = pp(pA0.y), w2 = pp(pA1.x), w3 = pp(pA1.y);
    float w4 = pp(pA2.x), w5 = pp(pA2.y), w6 = pp(pA3.x), w7 = pp(pA3.y);

    float y0 = step(cg + 0, qa.x, xq0); float e0 = err;
    float y1 = step(cg + 1, qa.y, xq1); float e1 = err;
    float y2 = step(cg + 2, qb.x, xq2); float e2 = err;
    float y3 = step(cg + 3, qb.y, xq3); float e3 = err;
    float y4 = step(cg + 4, qc.x, xq4); float e4 = err;
    float y5 = step(cg + 5, qc.y, xq5); float e5 = err;
    float y6 = step(cg + 6, qd.x, xq6); float e6 = err;
    float y7 = step(cg + 7, qd.y, xq7); float e7 = err;

    if ((unsigned)(cg + 0) < 511u) *(float2*)(yrow + cg + 0) = make_float2(y0, y1);
    if ((unsigned)(cg + 2) < 511u) *(float2*)(yrow + cg + 2) = make_float2(y2, y3);
    if ((unsigned)(cg + 4) < 511u) *(float2*)(yrow + cg + 4) = make_float2(y4, y5);
    if ((unsigned)(cg + 6) < 511u) *(float2*)(yrow + cg + 6) = make_float2(y6, y7);

    if (l63) {
      float* bw = bufW + (cg + 129);
      bw[0] = e0; bw[1] = e1; bw[2] = e2; bw[3] = e3;
      bw[4] = e4; bw[5] = e5; bw[6] = e6; bw[7] = e7;
    }

    xq0 = w0; xq1 = w1; xq2 = w2; xq3 = w3;
    xq4 = w4; xq5 = w5; xq6 = w6; xq7 = w7;
    pA0 = pB0; pA1 = pB1; pA2 = pB2; pA3 = pB3;
    pB0 = n0;  pB1 = n1;  pB2 = n2;  pB3 = n3;
    qa = fa; qb = fb; qc = fc; qd = fd;
    fa = h0; fb = h1; fc = h2; fd = h3;
  };

  for (int j = 0; j < NCH; ++j) {
    if (wave) {
      int need = j + LAG; if (need > NCH) need = NCH;
      while (__hip_atomic_load(&flags[wave - 1], __ATOMIC_RELAXED,
                               __HIP_MEMORY_SCOPE_WORKGROUP) < need)
        __builtin_amdgcn_s_sleep(1);
      __asm__ volatile("s_waitcnt lgkmcnt(0)" ::: "memory");
    }
    iter8(16 * j);
    iter8(16 * j + 8);
    if (l63) {
      __asm__ volatile("s_waitcnt lgkmcnt(0)" ::: "memory");
      __hip_atomic_store(&flags[wave], j + 1, __ATOMIC_RELAXED,
                         __HIP_MEMORY_SCOPE_WORKGROUP);
    }
  }
}

extern "C" void kernel_launch(void* const* d_in, const int* in_sizes, int n_in,
                              void* d_out, int out_size, void* d_ws, size_t ws_size,
                              hipStream_t stream) {
  const float* x = (const float*)d_in[0];
  float*       y = (float*)d_out;
  if (ws_size >= WS_NEED) {
    float* xp = (float*)((char*)d_ws + XP_OFF);
    pack_kernel<<<dim3(NIMG, NW), dim3(512), 0, stream>>>(x, xp);
    dither_packed<<<dim3(NIMG), dim3(512), 0, stream>>>(xp, y);
  } else {
    dither_direct<<<dim3(NIMG), dim3(512), 0, stream>>>(x, y);
  }
}